// Round 15
// baseline (2189.318 us; speedup 1.0000x reference)
//
#include <hip/hip_runtime.h>
#include <hip/hip_bf16.h>
#include <stdint.h>
#include <stddef.h>

#define Bb 16
#define Nn 512
#define Ee 6144
#define Dd 256
#define ROWS (Bb * Ee)   // 98304

typedef short bf16x8 __attribute__((ext_vector_type(8)));
typedef float f32x4 __attribute__((ext_vector_type(4)));

__device__ __forceinline__ unsigned short f2bf(float f) {
  union { float f; unsigned u; } v; v.f = f;
  return (unsigned short)((v.u + 0x7fffu + ((v.u >> 16) & 1u)) >> 16);
}
__device__ __forceinline__ float bf2f(unsigned short h) {
  union { unsigned u; float f; } v; v.u = ((unsigned)h) << 16;
  return v.f;
}

__device__ __forceinline__ void gload16(const void* g, void* l) {
  __builtin_amdgcn_global_load_lds(
      (const __attribute__((address_space(1))) void*)g,
      (__attribute__((address_space(3))) void*)l, 16, 0, 0);
}

// ---------------- weight transpose: f32 [K][N] -> bf16 [N][K], batched over z ----------------
__global__ void transpose_w(const float* __restrict__ in, unsigned short* __restrict__ out,
                            int K, int Ncol) {
  __shared__ float tile[32][33];
  const float* inb = in + (size_t)blockIdx.z * K * Ncol;
  unsigned short* outb = out + (size_t)blockIdx.z * K * Ncol;
  int bk = blockIdx.x * 32, bn = blockIdx.y * 32;
  int tx = threadIdx.x, ty = threadIdx.y;
#pragma unroll
  for (int i = 0; i < 32; i += 8)
    tile[ty + i][tx] = inb[(size_t)(bk + ty + i) * Ncol + (bn + tx)];
  __syncthreads();
#pragma unroll
  for (int i = 0; i < 32; i += 8)
    outb[(size_t)(bn + ty + i) * K + (bk + tx)] = f2bf(tile[tx][ty + i]);
}

// ---------------- atom_state init ----------------
__global__ void atom_init(const int* __restrict__ cls, const float* __restrict__ emb,
                          float* __restrict__ atom, unsigned short* __restrict__ atomBf) {
  int s_ = blockIdx.x, d = threadIdx.x;
  size_t o = (size_t)s_ * Dd + d;
  float v = emb[(size_t)cls[s_] * Dd + d];
  atom[o] = v;
  atomBf[o] = f2bf(v);
}

// ---------------- after node scatter: re-impose mask, refresh bf16 mirror ----------------
__global__ void atom_fix(const int* __restrict__ cls, const float* __restrict__ emb,
                         float* __restrict__ atom, unsigned short* __restrict__ atomBf) {
  int s_ = blockIdx.x, d = threadIdx.x;
  size_t o = (size_t)s_ * Dd + d;
  float v = (cls[s_] == 0) ? emb[d] : atom[o];
  atom[o] = v;
  atomBf[o] = f2bf(v);
}

// ---------------- RBF gemm: bond = rbf(dist) @ bond_W + b  -> split hi/lo bf16 ----------------
__global__ __launch_bounds__(256, 2) void gemm_rbf(
    const unsigned short* __restrict__ Wt, const float* __restrict__ bias,
    const float* __restrict__ dist, const float* __restrict__ centers,
    const float* __restrict__ gapP, unsigned short* __restrict__ bondHi,
    unsigned short* __restrict__ bondLo) {
  __shared__ __align__(16) unsigned short lA[128 * 64];
  __shared__ __align__(16) unsigned short lB[128 * 64];
  const int t = threadIdx.x;
  const int bm = blockIdx.x * 128, bn = blockIdx.y * 128;
  const int srow = t & 127, skc = (t >> 7) * 32;
  const int m = bm + srow;
  float dval = dist[m]; if (dval == 0.f) dval = 1.f;
  float gapv = *gapP;
  const unsigned short* pBt = Wt + (size_t)(bn + srow) * 128 + skc;
  const int wid = t >> 6, lane = t & 63;
  const int wm = (wid & 1) * 64, wn = (wid >> 1) * 64;
  const int fr = lane & 15, fk0 = (lane >> 4) * 8;
  f32x4 acc[4][4] = {};
  for (int k0 = 0; k0 < 128; k0 += 64) {
    union __align__(16) { unsigned short us[32]; bf16x8 v[4]; } ab, bb;
#pragma unroll
    for (int j = 0; j < 32; j++) {
      float x = dval - centers[k0 + skc + j];
      ab.us[j] = f2bf(__expf(-gapv * x * x));
    }
    const bf16x8* s = (const bf16x8*)(pBt + k0);
#pragma unroll
    for (int c = 0; c < 4; c++) bb.v[c] = s[c];
    __syncthreads();
#pragma unroll
    for (int c = 0; c < 4; c++) {
      int byteo = (skc + c * 8) * 2;
      int swz = byteo ^ ((srow & 7) << 4);
      *(bf16x8*)((char*)lA + srow * 128 + swz) = ab.v[c];
      *(bf16x8*)((char*)lB + srow * 128 + swz) = bb.v[c];
    }
    __syncthreads();
#pragma unroll
    for (int kk = 0; kk < 64; kk += 32) {
      bf16x8 af[4], bfq[4];
#pragma unroll
      for (int f = 0; f < 4; f++) {
        int r = wm + f * 16 + fr;
        af[f] = *(const bf16x8*)((const char*)lA + r * 128 + (((kk + fk0) * 2) ^ ((r & 7) << 4)));
        int cq = wn + f * 16 + fr;
        bfq[f] = *(const bf16x8*)((const char*)lB + cq * 128 + (((kk + fk0) * 2) ^ ((cq & 7) << 4)));
      }
#pragma unroll
      for (int i = 0; i < 4; i++)
#pragma unroll
        for (int j = 0; j < 4; j++)
          acc[i][j] = __builtin_amdgcn_mfma_f32_16x16x32_bf16(af[i], bfq[j], acc[i][j], 0, 0, 0);
    }
  }
#pragma unroll
  for (int i = 0; i < 4; i++)
#pragma unroll
    for (int j = 0; j < 4; j++) {
      int gcol = bn + wn + j * 16 + fr;
      float bvv = bias[gcol];
#pragma unroll
      for (int v = 0; v < 4; v++) {
        int grow = bm + wm + i * 16 + (lane >> 4) * 4 + v;
        float val = acc[i][j][v] + bvv;
        size_t o = (size_t)grow * Dd + gcol;
        unsigned short hi = f2bf(val);
        bondHi[o] = hi;
        bondLo[o] = f2bf(val - bf2f(hi));
      }
    }
}

// ---- 128x256 MFMA GEMM, BK=32, 8 waves (wave-tile 64x64), 48 KB LDS, 2 blocks/CU ----
// Same sync skeleton as the proven R6/R7 kernels: stage(t+1) -> compute(t) -> __syncthreads.
struct GP {
  const unsigned short* Wt;      // [NC][K] bf16
  const float* bias;             // [NC]
  const unsigned short* bondHi;  // [ROWS][256] bf16 (GEMM operand + master hi)
  unsigned short* bondLo;        // [ROWS][256] bf16 (master lo)
  const unsigned short* atomBf;  // [B*N][256] bf16 mirror
  const unsigned short* h1;      // [ROWS][512] bf16
  const int* conn;               // [ROWS][2]
  const float* dist;             // [ROWS]
  unsigned short* outH1;         // [ROWS][512]
  unsigned short* outBondHi;     // = bondHi (non-const alias)
  float* atomMaster;             // [B*N][256] f32 (node2 atomics)
};

#define A_EDGE1 0
#define A_NODE1 1
#define A_H1    2
#define EP_H1RELU 0
#define EP_EDGE2  1
#define EP_NODE2  2

template <int K, int NC, int AL, int EP>
__global__ __launch_bounds__(512, 4) void gemm128(GP p) {
  // A dbuf: 2 x 8 KB @0 (128 rows x 64 B); B dbuf: 2 x 16 KB @16384 (256 rows x 64 B).
  __shared__ __align__(16) char lds[49152];
  constexpr int BOFF = 16384;
  const int t = threadIdx.x;
  const int w = t >> 6, l = t & 63;
  constexpr int NT = NC / 256;

  // XCD-chunked bijective swizzle (gridDim.x % 8 == 0 for all launches)
  const int nwg = gridDim.x;
  const int q8 = nwg >> 3;
  const int sb = (blockIdx.x & 7) * q8 + (blockIdx.x >> 3);
  const int bn = (sb % NT) * 256;
  const int bm = (sb / NT) * 128;

  // staging: thread t owns A row t>>2 (1 gload) and B rows {t>>2, 128+(t>>2)} (2 gloads),
  // 16B chunk t&3, swizzle pre-applied to the GLOBAL address (LDS dest linear).
  const int srow = t >> 2;
  const int sswz = (((t & 3) ^ ((srow >> 1) & 3)) << 4);   // same for row and row+128

  const char* pA0; const char* pA1; const char* pA2;
  if (AL == A_H1) {
    pA0 = (const char*)p.h1 + (size_t)(bm + srow) * (K * 2) + sswz;
    pA1 = pA0; pA2 = pA0;
  } else {
    int gr = bm + srow;
    int b = gr / Ee;
    int i0 = p.conn[2 * gr], i1 = p.conn[2 * gr + 1];
    const char* bondRow = (const char*)p.bondHi + (size_t)gr * 512 + sswz;
    const char* srcRow  = (const char*)p.atomBf + ((size_t)b * Nn + i1) * 512 + sswz;
    const char* tgtRow  = (const char*)p.atomBf + ((size_t)b * Nn + i0) * 512 + sswz;
    if (AL == A_EDGE1) { pA0 = bondRow; pA1 = srcRow; pA2 = tgtRow; }
    else               { pA0 = srcRow;  pA1 = bondRow; pA2 = bondRow; }
  }
  const char* pB0 = (const char*)p.Wt + (size_t)(bn + srow) * (K * 2) + sswz;
  const char* pB1 = (const char*)p.Wt + (size_t)(bn + 128 + srow) * (K * 2) + sswz;

  const int fr = l & 15;
  const int q4 = l >> 4;            // 16B k-chunk selector within BK=32 row
  const int wm = (w >> 2) * 64;     // 2 wave-rows of 64
  const int wn = (w & 3) * 64;      // 4 wave-cols of 64

  f32x4 acc[4][4] = {};

  auto stage = [&](int pb, int k0) {
    const char* srcA;
    if (AL == A_H1)         srcA = pA0 + k0 * 2;
    else if (AL == A_EDGE1) { int s = k0 >> 8; srcA = (s == 0 ? pA0 : (s == 1 ? pA1 : pA2)) + (k0 & 255) * 2; }
    else                    srcA = (k0 < 256 ? pA0 : pA1) + (k0 & 255) * 2;
    gload16(srcA, lds + pb * 8192 + w * 1024);                         // + lane*16 by HW
    gload16(pB0 + k0 * 2, lds + BOFF + pb * 16384 + w * 1024);
    gload16(pB1 + k0 * 2, lds + BOFF + pb * 16384 + 8192 + w * 1024);
  };

  auto compute = [&](int pb) {
    bf16x8 av[4], bv[4];
#pragma unroll
    for (int f = 0; f < 4; f++) {
      int r = wm + f * 16 + fr;
      av[f] = *(const bf16x8*)(lds + pb * 8192 + r * 64 + ((q4 ^ ((r >> 1) & 3)) << 4));
    }
#pragma unroll
    for (int n = 0; n < 4; n++) {
      int rq = wn + n * 16 + fr;
      bv[n] = *(const bf16x8*)(lds + BOFF + pb * 16384 + rq * 64 + ((q4 ^ ((rq >> 1) & 3)) << 4));
    }
#pragma unroll
    for (int f = 0; f < 4; f++)
#pragma unroll
      for (int n = 0; n < 4; n++)
        acc[f][n] = __builtin_amdgcn_mfma_f32_16x16x32_bf16(av[f], bv[n], acc[f][n], 0, 0, 0);
  };

  constexpr int nT = K / 32;
  stage(0, 0);
  __syncthreads();
  for (int tt = 0; tt < nT; tt++) {
    int pb = tt & 1;
    if (tt + 1 < nT) stage(pb ^ 1, (tt + 1) * 32);
    compute(pb);
    __syncthreads();
  }

  // ---- epilogue ----
  float bias4[4];
#pragma unroll
  for (int n = 0; n < 4; n++) bias4[n] = p.bias[bn + wn + n * 16 + fr];

#pragma unroll
  for (int f = 0; f < 4; f++) {
#pragma unroll
    for (int v = 0; v < 4; v++) {
      int grow = bm + wm + f * 16 + q4 * 4 + v;
      if (EP == EP_H1RELU) {
#pragma unroll
        for (int n = 0; n < 4; n++) {
          int gcol = bn + wn + n * 16 + fr;
          float val = acc[f][n][v] + bias4[n];
          p.outH1[(size_t)grow * 512 + gcol] = f2bf(fmaxf(val, 0.f));
        }
      } else if (EP == EP_EDGE2) {
        if (p.dist[grow] != 0.f) {
#pragma unroll
          for (int n = 0; n < 4; n++) {
            int gcol = bn + wn + n * 16 + fr;
            size_t o = (size_t)grow * Dd + gcol;
            float cur = bf2f(p.bondHi[o]) + bf2f(p.bondLo[o]);
            float nv = cur + acc[f][n][v] + bias4[n];
            unsigned short hi = f2bf(nv);
            p.outBondHi[o] = hi;
            p.bondLo[o] = f2bf(nv - bf2f(hi));
          }
        }
      } else {  // EP_NODE2
        int b = grow / Ee;
        int tg = p.conn[2 * grow];
        float* dst = p.atomMaster + ((size_t)b * Nn + tg) * Dd;
#pragma unroll
        for (int n = 0; n < 4; n++) {
          int gcol = bn + wn + n * 16 + fr;
          atomicAdd(dst + gcol, acc[f][n][v] + bias4[n]);
        }
      }
    }
  }
}

// ---------------- final readout ----------------
__global__ void pool_k(const float* __restrict__ atom, const int* __restrict__ cls,
                       const float* __restrict__ meanEmb, const float* __restrict__ oW,
                       const float* __restrict__ ob, float* __restrict__ out) {
  __shared__ float w[Dd];
  __shared__ float red[256];
  __shared__ float redc[256];
  int b = blockIdx.x, t = threadIdx.x;
  w[t] = oW[t];
  __syncthreads();
  float sum = 0.f, cnt = 0.f;
  for (int n = t; n < Nn; n += 256) {
    int site = b * Nn + n;
    int c = cls[site];
    const float* a = atom + (size_t)site * Dd;
    float dot = 0.f;
    for (int d = 0; d < Dd; d++) dot += a[d] * w[d];
    if (c != 0) { sum += meanEmb[c] + dot + ob[0]; cnt += 1.f; }
  }
  red[t] = sum; redc[t] = cnt;
  __syncthreads();
  for (int s = 128; s > 0; s >>= 1) {
    if (t < s) { red[t] += red[t + s]; redc[t] += redc[t + s]; }
    __syncthreads();
  }
  if (t == 0) out[b] = red[0] / redc[0];
}

extern "C" void kernel_launch(void* const* d_in, const int* in_sizes, int n_in,
                              void* d_out, int out_size, void* d_ws, size_t ws_size,
                              hipStream_t stream) {
  const int* site_class = (const int*)d_in[0];
  const float* distance = (const float*)d_in[1];
  const int* conn       = (const int*)d_in[2];
  const float* atom_emb = (const float*)d_in[3];
  const float* mean_emb = (const float*)d_in[4];
  const float* centers  = (const float*)d_in[5];
  const float* gapP     = (const float*)d_in[6];
  const float* bond_W   = (const float*)d_in[7];
  const float* bond_b   = (const float*)d_in[8];
  const float* offset_W = (const float*)d_in[9];
  const float* offset_b = (const float*)d_in[10];
  const float* edge_W1  = (const float*)d_in[11];
  const float* edge_b1  = (const float*)d_in[12];
  const float* edge_W2  = (const float*)d_in[13];
  const float* edge_b2  = (const float*)d_in[14];
  const float* node_W1  = (const float*)d_in[15];
  const float* node_b1  = (const float*)d_in[16];
  const float* node_W2  = (const float*)d_in[17];
  const float* node_b2  = (const float*)d_in[18];

  char* ws = (char*)d_ws;
  float* atom            = (float*)(ws + 0);                    //   8,388,608
  unsigned short* atomBf = (unsigned short*)(ws + 8388608);     //   4,194,304
  unsigned short* bondHi = (unsigned short*)(ws + 12582912);    //  50,331,648
  unsigned short* bondLo = (unsigned short*)(ws + 62914560);    //  50,331,648
  unsigned short* h1     = (unsigned short*)(ws + 113246208);   // 100,663,296
  unsigned short* bWT    = (unsigned short*)(ws + 213909504);   //      65,536
  unsigned short* eW1T   = (unsigned short*)(ws + 213975040);   //   4,718,592
  unsigned short* eW2T   = (unsigned short*)(ws + 218693632);   //   1,572,864
  unsigned short* nW1T   = (unsigned short*)(ws + 220266496);   //   3,145,728
  unsigned short* nW2T   = (unsigned short*)(ws + 223412224);   //   1,572,864  (end 224,985,088)

  dim3 tb(32, 8);
  transpose_w<<<dim3(4, 8, 1), tb, 0, stream>>>(bond_W, bWT, 128, 256);
  transpose_w<<<dim3(24, 16, 6), tb, 0, stream>>>(edge_W1, eW1T, 768, 512);
  transpose_w<<<dim3(16, 8, 6), tb, 0, stream>>>(edge_W2, eW2T, 512, 256);
  transpose_w<<<dim3(16, 16, 6), tb, 0, stream>>>(node_W1, nW1T, 512, 512);
  transpose_w<<<dim3(16, 8, 6), tb, 0, stream>>>(node_W2, nW2T, 512, 256);

  atom_init<<<Bb * Nn, 256, 0, stream>>>(site_class, atom_emb, atom, atomBf);
  gemm_rbf<<<dim3(768, 2), 256, 0, stream>>>(bWT, bond_b, distance, centers, gapP, bondHi, bondLo);

  GP base{};
  base.conn = conn; base.dist = distance;
  base.bondHi = bondHi; base.bondLo = bondLo; base.atomBf = atomBf; base.h1 = h1;
  base.outH1 = h1; base.outBondHi = bondHi; base.atomMaster = atom;

  for (int i = 0; i < 6; i++) {
    {
      GP q = base;
      q.Wt = eW1T + (size_t)i * 512 * 768; q.bias = edge_b1 + i * 512;
      gemm128<768, 512, A_EDGE1, EP_H1RELU><<<1536, 512, 0, stream>>>(q);
    }
    {
      GP q = base;
      q.Wt = eW2T + (size_t)i * 256 * 512; q.bias = edge_b2 + i * 256;
      gemm128<512, 256, A_H1, EP_EDGE2><<<768, 512, 0, stream>>>(q);
    }
    {
      GP q = base;
      q.Wt = nW1T + (size_t)i * 512 * 512; q.bias = node_b1 + i * 512;
      gemm128<512, 512, A_NODE1, EP_H1RELU><<<1536, 512, 0, stream>>>(q);
    }
    {
      GP q = base;
      q.Wt = nW2T + (size_t)i * 256 * 512; q.bias = node_b2 + i * 256;
      gemm128<512, 256, A_H1, EP_NODE2><<<768, 512, 0, stream>>>(q);
    }
    atom_fix<<<Bb * Nn, 256, 0, stream>>>(site_class, atom_emb, atom, atomBf);
  }

  pool_k<<<Bb, 256, 0, stream>>>(atom, site_class, mean_emb, offset_W, offset_b, (float*)d_out);
}

// Round 16
// 1948.004 us; speedup vs baseline: 1.1239x; 1.1239x over previous
//
#include <hip/hip_runtime.h>
#include <hip/hip_bf16.h>
#include <stdint.h>
#include <stddef.h>

#define Bb 16
#define Nn 512
#define Ee 6144
#define Dd 256
#define ROWS (Bb * Ee)   // 98304

typedef short bf16x8 __attribute__((ext_vector_type(8)));
typedef float f32x4 __attribute__((ext_vector_type(4)));

__device__ __forceinline__ unsigned short f2bf(float f) {
  union { float f; unsigned u; } v; v.f = f;
  return (unsigned short)((v.u + 0x7fffu + ((v.u >> 16) & 1u)) >> 16);
}
__device__ __forceinline__ float bf2f(unsigned short h) {
  union { unsigned u; float f; } v; v.u = ((unsigned)h) << 16;
  return v.f;
}

__device__ __forceinline__ void gload16(const void* g, void* l) {
  __builtin_amdgcn_global_load_lds(
      (const __attribute__((address_space(1))) void*)g,
      (__attribute__((address_space(3))) void*)l, 16, 0, 0);
}

// ---------------- weight transpose: f32 [K][N] -> bf16 [N][K], batched over z ----------------
__global__ void transpose_w(const float* __restrict__ in, unsigned short* __restrict__ out,
                            int K, int Ncol) {
  __shared__ float tile[32][33];
  const float* inb = in + (size_t)blockIdx.z * K * Ncol;
  unsigned short* outb = out + (size_t)blockIdx.z * K * Ncol;
  int bk = blockIdx.x * 32, bn = blockIdx.y * 32;
  int tx = threadIdx.x, ty = threadIdx.y;
#pragma unroll
  for (int i = 0; i < 32; i += 8)
    tile[ty + i][tx] = inb[(size_t)(bk + ty + i) * Ncol + (bn + tx)];
  __syncthreads();
#pragma unroll
  for (int i = 0; i < 32; i += 8)
    outb[(size_t)(bn + ty + i) * K + (bk + tx)] = f2bf(tile[tx][ty + i]);
}

// ---------------- atom_state init ----------------
__global__ void atom_init(const int* __restrict__ cls, const float* __restrict__ emb,
                          float* __restrict__ atom, unsigned short* __restrict__ atomBf) {
  int s_ = blockIdx.x, d = threadIdx.x;
  size_t o = (size_t)s_ * Dd + d;
  float v = emb[(size_t)cls[s_] * Dd + d];
  atom[o] = v;
  atomBf[o] = f2bf(v);
}

// ---------------- after node scatter: re-impose mask, refresh bf16 mirror ----------------
__global__ void atom_fix(const int* __restrict__ cls, const float* __restrict__ emb,
                         float* __restrict__ atom, unsigned short* __restrict__ atomBf) {
  int s_ = blockIdx.x, d = threadIdx.x;
  size_t o = (size_t)s_ * Dd + d;
  float v = (cls[s_] == 0) ? emb[d] : atom[o];
  atom[o] = v;
  atomBf[o] = f2bf(v);
}

// ---------------- RBF gemm: bond = rbf(dist) @ bond_W + b  -> split hi/lo bf16 ----------------
__global__ __launch_bounds__(256, 2) void gemm_rbf(
    const unsigned short* __restrict__ Wt, const float* __restrict__ bias,
    const float* __restrict__ dist, const float* __restrict__ centers,
    const float* __restrict__ gapP, unsigned short* __restrict__ bondHi,
    unsigned short* __restrict__ bondLo) {
  __shared__ __align__(16) unsigned short lA[128 * 64];
  __shared__ __align__(16) unsigned short lB[128 * 64];
  const int t = threadIdx.x;
  const int bm = blockIdx.x * 128, bn = blockIdx.y * 128;
  const int srow = t & 127, skc = (t >> 7) * 32;
  const int m = bm + srow;
  float dval = dist[m]; if (dval == 0.f) dval = 1.f;
  float gapv = *gapP;
  const unsigned short* pBt = Wt + (size_t)(bn + srow) * 128 + skc;
  const int wid = t >> 6, lane = t & 63;
  const int wm = (wid & 1) * 64, wn = (wid >> 1) * 64;
  const int fr = lane & 15, fk0 = (lane >> 4) * 8;
  f32x4 acc[4][4] = {};
  for (int k0 = 0; k0 < 128; k0 += 64) {
    union __align__(16) { unsigned short us[32]; bf16x8 v[4]; } ab, bb;
#pragma unroll
    for (int j = 0; j < 32; j++) {
      float x = dval - centers[k0 + skc + j];
      ab.us[j] = f2bf(__expf(-gapv * x * x));
    }
    const bf16x8* s = (const bf16x8*)(pBt + k0);
#pragma unroll
    for (int c = 0; c < 4; c++) bb.v[c] = s[c];
    __syncthreads();
#pragma unroll
    for (int c = 0; c < 4; c++) {
      int byteo = (skc + c * 8) * 2;
      int swz = byteo ^ ((srow & 7) << 4);
      *(bf16x8*)((char*)lA + srow * 128 + swz) = ab.v[c];
      *(bf16x8*)((char*)lB + srow * 128 + swz) = bb.v[c];
    }
    __syncthreads();
#pragma unroll
    for (int kk = 0; kk < 64; kk += 32) {
      bf16x8 af[4], bfq[4];
#pragma unroll
      for (int f = 0; f < 4; f++) {
        int r = wm + f * 16 + fr;
        af[f] = *(const bf16x8*)((const char*)lA + r * 128 + (((kk + fk0) * 2) ^ ((r & 7) << 4)));
        int cq = wn + f * 16 + fr;
        bfq[f] = *(const bf16x8*)((const char*)lB + cq * 128 + (((kk + fk0) * 2) ^ ((cq & 7) << 4)));
      }
#pragma unroll
      for (int i = 0; i < 4; i++)
#pragma unroll
        for (int j = 0; j < 4; j++)
          acc[i][j] = __builtin_amdgcn_mfma_f32_16x16x32_bf16(af[i], bfq[j], acc[i][j], 0, 0, 0);
    }
  }
#pragma unroll
  for (int i = 0; i < 4; i++)
#pragma unroll
    for (int j = 0; j < 4; j++) {
      int gcol = bn + wn + j * 16 + fr;
      float bvv = bias[gcol];
#pragma unroll
      for (int v = 0; v < 4; v++) {
        int grow = bm + wm + i * 16 + (lane >> 4) * 4 + v;
        float val = acc[i][j][v] + bvv;
        size_t o = (size_t)grow * Dd + gcol;
        unsigned short hi = f2bf(val);
        bondHi[o] = hi;
        bondLo[o] = f2bf(val - bf2f(hi));
      }
    }
}

// ---------------- 128x128 MFMA GEMM, 512 threads (8 waves), BK=64, 2 blocks/CU ----------------
struct GP {
  const unsigned short* Wt;      // [NC][K] bf16
  const float* bias;             // [NC]
  const unsigned short* bondHi;  // [ROWS][256] bf16 (GEMM operand + master hi)
  unsigned short* bondLo;        // [ROWS][256] bf16 (master lo)
  const unsigned short* atomBf;  // [B*N][256] bf16 mirror
  const unsigned short* h1;      // [ROWS][512] bf16
  const int* conn;               // [ROWS][2]
  const float* dist;             // [ROWS]
  unsigned short* outH1;         // [ROWS][512]
  unsigned short* outBondHi;     // = bondHi (non-const alias)
  float* atomMaster;             // [B*N][256] f32 (node2 atomics)
};

#define A_EDGE1 0
#define A_NODE1 1
#define A_H1    2
#define EP_H1RELU 0
#define EP_EDGE2  1
#define EP_NODE2  2

template <int K, int NC, int AL, int EP>
__global__ __launch_bounds__(512, 4) void gemm128(GP p) {
  __shared__ __align__(16) char lds[65536];   // A dbuf 2x16KB @0, B dbuf 2x16KB @32768
  constexpr int BOFF = 32768;
  const int t = threadIdx.x;
  const int w = t >> 6, l = t & 63;
  constexpr int NT = NC / 128;

  // XCD-chunked bijective swizzle (gridDim.x % 8 == 0 for all launches)
  const int nwg = gridDim.x;
  const int q8 = nwg >> 3;
  const int sb = (blockIdx.x & 7) * q8 + (blockIdx.x >> 3);
  const int bn = (sb % NT) * 128;
  const int bm = (sb / NT) * 128;

  // staging source pointers (swizzle pre-applied to GLOBAL address; LDS dest linear)
  const char* pA0[2]; const char* pA1[2]; const char* pA2[2]; const char* pB[2];
#pragma unroll
  for (int i = 0; i < 2; i++) {
    int r = (w * 2 + i) * 8 + (l >> 3);      // tile row 0..127
    int swz = (((l & 7) ^ (r & 7)) << 4);
    if (AL == A_H1) {
      pA0[i] = (const char*)p.h1 + (size_t)(bm + r) * (K * 2) + swz;
      pA1[i] = pA0[i]; pA2[i] = pA0[i];
    } else {
      int gr = bm + r;
      int b = gr / Ee;
      int i0 = p.conn[2 * gr], i1 = p.conn[2 * gr + 1];
      const char* bondRow = (const char*)p.bondHi + (size_t)gr * 512 + swz;
      const char* srcRow  = (const char*)p.atomBf + ((size_t)b * Nn + i1) * 512 + swz;
      const char* tgtRow  = (const char*)p.atomBf + ((size_t)b * Nn + i0) * 512 + swz;
      if (AL == A_EDGE1) { pA0[i] = bondRow; pA1[i] = srcRow; pA2[i] = tgtRow; }
      else               { pA0[i] = srcRow;  pA1[i] = bondRow; pA2[i] = bondRow; }
    }
    pB[i] = (const char*)p.Wt + (size_t)(bn + r) * (K * 2) + swz;
  }

  const int fr = l & 15;
  const int q4 = l >> 4;
  const int wm = (w >> 2) * 64;     // 2 wave-rows of 64
  const int wn = (w & 3) * 32;      // 4 wave-cols of 32

  f32x4 acc[4][2] = {};

  auto stage = [&](int pb, int k0) {
#pragma unroll
    for (int i = 0; i < 2; i++) {
      const char* src;
      if (AL == A_H1)         src = pA0[i] + k0 * 2;
      else if (AL == A_EDGE1) { int s = k0 >> 8; src = (s == 0 ? pA0[i] : (s == 1 ? pA1[i] : pA2[i])) + (k0 & 255) * 2; }
      else                    src = (k0 < 256 ? pA0[i] : pA1[i]) + (k0 & 255) * 2;
      gload16(src, lds + pb * 16384 + (w * 2 + i) * 1024);
      gload16(pB[i] + k0 * 2, lds + BOFF + pb * 16384 + (w * 2 + i) * 1024);
    }
  };

  auto compute = [&](int pb) {
#pragma unroll
    for (int kk = 0; kk < 2; kk++) {
      const int ck = kk * 4 + q4;
      bf16x8 av[4], bv[2];
#pragma unroll
      for (int f = 0; f < 4; f++) {
        int r = wm + f * 16 + fr;
        av[f] = *(const bf16x8*)(lds + pb * 16384 + r * 128 + ((ck ^ (r & 7)) << 4));
      }
#pragma unroll
      for (int n = 0; n < 2; n++) {
        int rq = wn + n * 16 + fr;
        bv[n] = *(const bf16x8*)(lds + BOFF + pb * 16384 + rq * 128 + ((ck ^ (rq & 7)) << 4));
      }
#pragma unroll
      for (int f = 0; f < 4; f++)
#pragma unroll
        for (int n = 0; n < 2; n++)
          acc[f][n] = __builtin_amdgcn_mfma_f32_16x16x32_bf16(av[f], bv[n], acc[f][n], 0, 0, 0);
    }
  };

  constexpr int nT = K / 64;
  stage(0, 0);
  __syncthreads();
  for (int tt = 0; tt < nT; tt++) {
    int pb = tt & 1;
    if (tt + 1 < nT) stage(pb ^ 1, (tt + 1) * 64);
    compute(pb);
    __syncthreads();
  }

  // ---- epilogue ----
  float bias2[2];
#pragma unroll
  for (int n = 0; n < 2; n++) bias2[n] = p.bias[bn + wn + n * 16 + fr];

#pragma unroll
  for (int f = 0; f < 4; f++) {
#pragma unroll
    for (int v = 0; v < 4; v++) {
      int grow = bm + wm + f * 16 + q4 * 4 + v;
      if (EP == EP_H1RELU) {
#pragma unroll
        for (int n = 0; n < 2; n++) {
          int gcol = bn + wn + n * 16 + fr;
          float val = acc[f][n][v] + bias2[n];
          p.outH1[(size_t)grow * 512 + gcol] = f2bf(fmaxf(val, 0.f));
        }
      } else if (EP == EP_EDGE2) {
        if (p.dist[grow] != 0.f) {
#pragma unroll
          for (int n = 0; n < 2; n++) {
            int gcol = bn + wn + n * 16 + fr;
            size_t o = (size_t)grow * Dd + gcol;
            float cur = bf2f(p.bondHi[o]) + bf2f(p.bondLo[o]);
            float nv = cur + acc[f][n][v] + bias2[n];
            unsigned short hi = f2bf(nv);
            p.outBondHi[o] = hi;
            p.bondLo[o] = f2bf(nv - bf2f(hi));
          }
        }
      } else {  // EP_NODE2
        int b = grow / Ee;
        int tg = p.conn[2 * grow];
        float* dst = p.atomMaster + ((size_t)b * Nn + tg) * Dd;
#pragma unroll
        for (int n = 0; n < 2; n++) {
          int gcol = bn + wn + n * 16 + fr;
          atomicAdd(dst + gcol, acc[f][n][v] + bias2[n]);
        }
      }
    }
  }
}

// ---------------- final readout ----------------
__global__ void pool_k(const float* __restrict__ atom, const int* __restrict__ cls,
                       const float* __restrict__ meanEmb, const float* __restrict__ oW,
                       const float* __restrict__ ob, float* __restrict__ out) {
  __shared__ float w[Dd];
  __shared__ float red[256];
  __shared__ float redc[256];
  int b = blockIdx.x, t = threadIdx.x;
  w[t] = oW[t];
  __syncthreads();
  float sum = 0.f, cnt = 0.f;
  for (int n = t; n < Nn; n += 256) {
    int site = b * Nn + n;
    int c = cls[site];
    const float* a = atom + (size_t)site * Dd;
    float dot = 0.f;
    for (int d = 0; d < Dd; d++) dot += a[d] * w[d];
    if (c != 0) { sum += meanEmb[c] + dot + ob[0]; cnt += 1.f; }
  }
  red[t] = sum; redc[t] = cnt;
  __syncthreads();
  for (int s = 128; s > 0; s >>= 1) {
    if (t < s) { red[t] += red[t + s]; redc[t] += redc[t + s]; }
    __syncthreads();
  }
  if (t == 0) out[b] = red[0] / redc[0];
}

extern "C" void kernel_launch(void* const* d_in, const int* in_sizes, int n_in,
                              void* d_out, int out_size, void* d_ws, size_t ws_size,
                              hipStream_t stream) {
  const int* site_class = (const int*)d_in[0];
  const float* distance = (const float*)d_in[1];
  const int* conn       = (const int*)d_in[2];
  const float* atom_emb = (const float*)d_in[3];
  const float* mean_emb = (const float*)d_in[4];
  const float* centers  = (const float*)d_in[5];
  const float* gapP     = (const float*)d_in[6];
  const float* bond_W   = (const float*)d_in[7];
  const float* bond_b   = (const float*)d_in[8];
  const float* offset_W = (const float*)d_in[9];
  const float* offset_b = (const float*)d_in[10];
  const float* edge_W1  = (const float*)d_in[11];
  const float* edge_b1  = (const float*)d_in[12];
  const float* edge_W2  = (const float*)d_in[13];
  const float* edge_b2  = (const float*)d_in[14];
  const float* node_W1  = (const float*)d_in[15];
  const float* node_b1  = (const float*)d_in[16];
  const float* node_W2  = (const float*)d_in[17];
  const float* node_b2  = (const float*)d_in[18];

  char* ws = (char*)d_ws;
  float* atom            = (float*)(ws + 0);                    //   8,388,608
  unsigned short* atomBf = (unsigned short*)(ws + 8388608);     //   4,194,304
  unsigned short* bondHi = (unsigned short*)(ws + 12582912);    //  50,331,648
  unsigned short* bondLo = (unsigned short*)(ws + 62914560);    //  50,331,648
  unsigned short* h1     = (unsigned short*)(ws + 113246208);   // 100,663,296
  unsigned short* bWT    = (unsigned short*)(ws + 213909504);   //      65,536
  unsigned short* eW1T   = (unsigned short*)(ws + 213975040);   //   4,718,592
  unsigned short* eW2T   = (unsigned short*)(ws + 218693632);   //   1,572,864
  unsigned short* nW1T   = (unsigned short*)(ws + 220266496);   //   3,145,728
  unsigned short* nW2T   = (unsigned short*)(ws + 223412224);   //   1,572,864  (end 224,985,088)

  dim3 tb(32, 8);
  transpose_w<<<dim3(4, 8, 1), tb, 0, stream>>>(bond_W, bWT, 128, 256);
  transpose_w<<<dim3(24, 16, 6), tb, 0, stream>>>(edge_W1, eW1T, 768, 512);
  transpose_w<<<dim3(16, 8, 6), tb, 0, stream>>>(edge_W2, eW2T, 512, 256);
  transpose_w<<<dim3(16, 16, 6), tb, 0, stream>>>(node_W1, nW1T, 512, 512);
  transpose_w<<<dim3(16, 8, 6), tb, 0, stream>>>(node_W2, nW2T, 512, 256);

  atom_init<<<Bb * Nn, 256, 0, stream>>>(site_class, atom_emb, atom, atomBf);
  gemm_rbf<<<dim3(768, 2), 256, 0, stream>>>(bWT, bond_b, distance, centers, gapP, bondHi, bondLo);

  GP base{};
  base.conn = conn; base.dist = distance;
  base.bondHi = bondHi; base.bondLo = bondLo; base.atomBf = atomBf; base.h1 = h1;
  base.outH1 = h1; base.outBondHi = bondHi; base.atomMaster = atom;

  for (int i = 0; i < 6; i++) {
    {
      GP q = base;
      q.Wt = eW1T + (size_t)i * 512 * 768; q.bias = edge_b1 + i * 512;
      gemm128<768, 512, A_EDGE1, EP_H1RELU><<<3072, 512, 0, stream>>>(q);
    }
    {
      GP q = base;
      q.Wt = eW2T + (size_t)i * 256 * 512; q.bias = edge_b2 + i * 256;
      gemm128<512, 256, A_H1, EP_EDGE2><<<1536, 512, 0, stream>>>(q);
    }
    {
      GP q = base;
      q.Wt = nW1T + (size_t)i * 512 * 512; q.bias = node_b1 + i * 512;
      gemm128<512, 512, A_NODE1, EP_H1RELU><<<3072, 512, 0, stream>>>(q);
    }
    {
      GP q = base;
      q.Wt = nW2T + (size_t)i * 256 * 512; q.bias = node_b2 + i * 256;
      gemm128<512, 256, A_H1, EP_NODE2><<<1536, 512, 0, stream>>>(q);
    }
    atom_fix<<<Bb * Nn, 256, 0, stream>>>(site_class, atom_emb, atom, atomBf);
  }

  pool_k<<<Bb, 256, 0, stream>>>(atom, site_class, mean_emb, offset_W, offset_b, (float*)d_out);
}